// Round 2
// baseline (261.354 us; speedup 1.0000x reference)
//
#include <hip/hip_runtime.h>
#include <math.h>

#define NN 512
#define HH 64
#define NLAYERS 4
#define LN_EPS 1e-5f

// ---------------------------------------------------------------------------
// Workspace layout (floats):
//   [full mode only] EAT : NN*NN*6  edge_attr dst-major: EAT[(j*NN+i)*6+k]
//   h, Pd, Qs, Rv, acc, h2 : NN*HH each
//   Sq  : NN       Sq[i] = sum_u Qs[i,u]*att_w2[l][u]  (linear score part)
// Pd = h@att_w1[0:64]+att_b1 (dst part); Qs = h@att_w1[64:128] (src part);
// Rv = h@val_w1[0:64]+val_b1 (src part); acc = sum_i alpha_i*relu(zv_i).
// Per-dst-constant score terms (0.6*Pd[j]@wa2, att_b2) cancel in softmax.
// ---------------------------------------------------------------------------

__global__ void k_transpose(const float* __restrict__ ea, float* __restrict__ eat) {
    int t = blockIdx.x * 256 + threadIdx.x;      // t = j*NN + i (output index)
    int i = t & (NN - 1);
    int j = t >> 9;
    int e = i * NN + j;                          // edge (src=i, dst=j)
#pragma unroll
    for (int k = 0; k < 6; ++k) eat[(size_t)t * 6 + k] = ea[(size_t)e * 6 + k];
}

// Encoder: h = relu(x@enc_w1+b1)@enc_w2+b2, then prep Pd/Qs/Rv/Sq for layer 0.
__global__ void k_encoder(const float* __restrict__ x,
                          const float* __restrict__ ew1, const float* __restrict__ eb1,
                          const float* __restrict__ ew2, const float* __restrict__ eb2,
                          const float* __restrict__ aw1, const float* __restrict__ ab1,
                          const float* __restrict__ wa2, const float* __restrict__ vw1,
                          const float* __restrict__ vb1,
                          float* __restrict__ h, float* __restrict__ Pd,
                          float* __restrict__ Qs, float* __restrict__ Rv,
                          float* __restrict__ Sq) {
    int j = blockIdx.x, d = threadIdx.x;         // 64 threads
    __shared__ float xs[6], t1[HH], hs[HH];
    if (d < 6) xs[d] = x[j * 6 + d];
    __syncthreads();
    float z = eb1[d];
#pragma unroll
    for (int k = 0; k < 6; ++k) z += xs[k] * ew1[k * HH + d];
    t1[d] = fmaxf(z, 0.f);
    __syncthreads();
    float z2 = eb2[d];
    for (int k = 0; k < HH; ++k) z2 += t1[k] * ew2[k * HH + d];
    h[j * HH + d] = z2;
    hs[d] = z2;
    __syncthreads();
    float p = ab1[d], q = 0.f, r = vb1[d];
    for (int k = 0; k < HH; ++k) {
        float hv = hs[k];
        p += hv * aw1[k * HH + d];
        q += hv * aw1[(HH + k) * HH + d];
        r += hv * vw1[k * HH + d];
    }
    Pd[j * HH + d] = p;
    Qs[j * HH + d] = q;
    Rv[j * HH + d] = r;
    float sq = q * wa2[d];
#pragma unroll
    for (int o = 32; o; o >>= 1) sq += __shfl_xor(sq, o);
    if (d == 0) Sq[j] = sq;
}

// Edge kernel: one block per dst node j. Dense attention over all 512 srcs.
// slot = lane>>3 (8 srcs in flight / wave), dp = lane&7 (8 out-dims / lane).
template <bool TRANS>
__launch_bounds__(256)
__global__ void k_edge(const float* __restrict__ easrc,
                       const float* __restrict__ Pd, const float* __restrict__ Qs,
                       const float* __restrict__ Rv, const float* __restrict__ Sq,
                       const float* __restrict__ waE,   // att_w1[l] rows 128..133 (6x64)
                       const float* __restrict__ wa2v,  // att_w2[l] (64)
                       const float* __restrict__ wvE,   // val_w1[l] rows 64..69 (6x64)
                       float* __restrict__ accv) {
    const int j = blockIdx.x;
    const int tid = threadIdx.x;
    const int lane = tid & 63;
    const int w = tid >> 6;        // wave 0..3
    const int slot = lane >> 3;    // 0..7
    const int dp = lane & 7;       // 0..7
    const int d0 = dp * 8;

    __shared__ __align__(16) float ea_s[NN * 6];   // 12 KB
    __shared__ __align__(16) float Sq_s[NN];       // 2 KB
    __shared__ float a_s[NN];                      // 2 KB
    __shared__ float red_m[4], red_s[4];
    __shared__ float accs[4][HH];

    if (TRANS) {
        const float4* s4 = (const float4*)(easrc + (size_t)j * (NN * 6));
        float4* d4 = (float4*)ea_s;
#pragma unroll
        for (int p = 0; p < 3; ++p) d4[tid + 256 * p] = s4[tid + 256 * p];
    } else {
#pragma unroll
        for (int rep = 0; rep < 2; ++rep) {
            int i = tid + rep * 256;
            const float2* s2 = (const float2*)(easrc + ((size_t)i * NN + j) * 6);
            float2 a0 = s2[0], a1 = s2[1], a2 = s2[2];
            ea_s[i * 6 + 0] = a0.x; ea_s[i * 6 + 1] = a0.y;
            ea_s[i * 6 + 2] = a1.x; ea_s[i * 6 + 3] = a1.y;
            ea_s[i * 6 + 4] = a2.x; ea_s[i * 6 + 5] = a2.y;
        }
    }
    if (tid < 128) ((float4*)Sq_s)[tid] = ((const float4*)Sq)[tid];

    // register-cached weights (per-lane slice of 8 dims)
    float WA[6][8], WV[6][8], wa2raw[8], wa2r[8], pdr[8];
#pragma unroll
    for (int k = 0; k < 6; ++k)
#pragma unroll
        for (int u = 0; u < 8; ++u) {
            WA[k][u] = waE[k * HH + d0 + u];
            WV[k][u] = wvE[k * HH + d0 + u];
        }
#pragma unroll
    for (int u = 0; u < 8; ++u) {
        wa2raw[u] = wa2v[d0 + u];
        pdr[u] = Pd[(size_t)j * HH + d0 + u];
    }
    // w6s[k] = 0.6 * sum_u WA[k][u]*wa2[u]  (linear edge-attr score term)
    float w6s[6];
#pragma unroll
    for (int k = 0; k < 6; ++k) {
        float t = 0.f;
#pragma unroll
        for (int u = 0; u < 8; ++u) t += WA[k][u] * wa2raw[u];
        t += __shfl_xor(t, 1);
        t += __shfl_xor(t, 2);
        t += __shfl_xor(t, 4);
        w6s[k] = 0.6f * t;
    }
#pragma unroll
    for (int u = 0; u < 8; ++u) wa2r[u] = 0.4f * wa2raw[u];  // |z| coefficient

    __syncthreads();   // ea_s / Sq_s ready

    // ---- phase 1: scores. a(i) = 0.6*(Sq[i] + ea.w6) + 0.4*sum_u |z_u|*wa2[u]
    const int ibw = w * 128;
    float lmax = -1e30f;
    for (int it = 0; it < 16; ++it) {
        const int i = ibw + it * 8 + slot;
        const float4* q4 = (const float4*)(Qs + (size_t)i * HH + d0);
        float4 qa = q4[0], qb = q4[1];
        float qv[8] = {qa.x, qa.y, qa.z, qa.w, qb.x, qb.y, qb.z, qb.w};
        float eav[6];
#pragma unroll
        for (int k = 0; k < 6; ++k) eav[k] = ea_s[i * 6 + k];
        float part = 0.f;
#pragma unroll
        for (int u = 0; u < 8; ++u) {
            float z = pdr[u] + qv[u];
#pragma unroll
            for (int k = 0; k < 6; ++k) z += eav[k] * WA[k][u];
            part += fabsf(z) * wa2r[u];
        }
        part += __shfl_xor(part, 1);
        part += __shfl_xor(part, 2);
        part += __shfl_xor(part, 4);
        float lin = 0.6f * Sq_s[i];
#pragma unroll
        for (int k = 0; k < 6; ++k) lin += eav[k] * w6s[k];
        float a = lin + part;
        if (dp == 0) a_s[i] = a;
        lmax = fmaxf(lmax, a);
    }
#pragma unroll
    for (int o = 32; o; o >>= 1) lmax = fmaxf(lmax, __shfl_xor(lmax, o));
    if (lane == 0) red_m[w] = lmax;
    __syncthreads();
    const float m = fmaxf(fmaxf(red_m[0], red_m[1]), fmaxf(red_m[2], red_m[3]));

    // ---- exp + sum ----
    float lsum = 0.f;
#pragma unroll
    for (int rep = 0; rep < 2; ++rep) {
        int i = tid + rep * 256;
        float e = expf(a_s[i] - m);
        a_s[i] = e;
        lsum += e;
    }
#pragma unroll
    for (int o = 32; o; o >>= 1) lsum += __shfl_xor(lsum, o);
    if (lane == 0) red_s[w] = lsum;
    __syncthreads();   // covers a_s updates + red_s
    const float s = red_s[0] + red_s[1] + red_s[2] + red_s[3];

    // ---- phase 2: weighted aggregate of relu(value-layer-1) ----
    float acc[8] = {0.f, 0.f, 0.f, 0.f, 0.f, 0.f, 0.f, 0.f};
    for (int it = 0; it < 16; ++it) {
        const int i = ibw + it * 8 + slot;
        const float4* r4 = (const float4*)(Rv + (size_t)i * HH + d0);
        float4 ra = r4[0], rb = r4[1];
        float rv[8] = {ra.x, ra.y, ra.z, ra.w, rb.x, rb.y, rb.z, rb.w};
        float eav[6];
#pragma unroll
        for (int k = 0; k < 6; ++k) eav[k] = ea_s[i * 6 + k];
        const float wi = a_s[i];
#pragma unroll
        for (int u = 0; u < 8; ++u) {
            float z = rv[u];
#pragma unroll
            for (int k = 0; k < 6; ++k) z += eav[k] * WV[k][u];
            acc[u] += wi * fmaxf(z, 0.f);
        }
    }
#pragma unroll
    for (int u = 0; u < 8; ++u) {
        acc[u] += __shfl_xor(acc[u], 8);
        acc[u] += __shfl_xor(acc[u], 16);
        acc[u] += __shfl_xor(acc[u], 32);
    }
    if (slot == 0) {
#pragma unroll
        for (int u = 0; u < 8; ++u) accs[w][d0 + u] = acc[u];
    }
    __syncthreads();
    if (tid < HH) {
        float tot = (accs[0][tid] + accs[1][tid] + accs[2][tid] + accs[3][tid]) / s;
        accv[(size_t)j * HH + tid] = tot;
    }
}

// Node kernel, split-K over 4 waves: agg = acc@val_w2+b2;
// u = relu([h,agg]@upd_w1+b)@upd_w2+b; r = u+h; LN; optional next-layer prep.
__launch_bounds__(256)
__global__ void k_node(const float* __restrict__ h_in, const float* __restrict__ accv,
                       const float* __restrict__ wv2, const float* __restrict__ vb2,
                       const float* __restrict__ uw1, const float* __restrict__ ub1,
                       const float* __restrict__ uw2, const float* __restrict__ ub2,
                       const float* __restrict__ lng, const float* __restrict__ lnb,
                       float* __restrict__ h_out,
                       const float* __restrict__ aw1n, const float* __restrict__ ab1n,
                       const float* __restrict__ wa2n, const float* __restrict__ vw1n,
                       const float* __restrict__ vb1n,
                       float* __restrict__ Pd, float* __restrict__ Qs,
                       float* __restrict__ Rv, float* __restrict__ Sq,
                       int do_prep) {
    const int j = blockIdx.x;
    const int tid = threadIdx.x;
    const int d = tid & 63;
    const int w = tid >> 6;        // wave 0..3
    __shared__ float av[HH], uin[2 * HH], r1[HH], hs[HH];
    __shared__ float part[4][HH], partQ[4][HH], partR[4][HH];

    float hv = h_in[(size_t)j * HH + d];
    if (w == 0) { av[d] = accv[(size_t)j * HH + d]; uin[d] = hv; }
    __syncthreads();

    // agg = acc @ val_w2 + vb2   (16 k's per wave)
    float p = (w == 0) ? vb2[d] : 0.f;
    for (int k = w * 16; k < w * 16 + 16; ++k) p += av[k] * wv2[k * HH + d];
    part[w][d] = p;
    __syncthreads();
    if (w == 0) uin[HH + d] = part[0][d] + part[1][d] + part[2][d] + part[3][d];
    __syncthreads();

    // t = uin @ upd_w1 + ub1   (32 c's per wave)
    float t = (w == 0) ? ub1[d] : 0.f;
    for (int c = w * 32; c < w * 32 + 32; ++c) t += uin[c] * uw1[c * HH + d];
    part[w][d] = t;
    __syncthreads();
    if (w == 0) r1[d] = fmaxf(part[0][d] + part[1][d] + part[2][d] + part[3][d], 0.f);
    __syncthreads();

    // u = r1 @ upd_w2 + ub2
    float u = (w == 0) ? ub2[d] : 0.f;
    for (int k = w * 16; k < w * 16 + 16; ++k) u += r1[k] * uw2[k * HH + d];
    part[w][d] = u;
    __syncthreads();
    float uu = part[0][d] + part[1][d] + part[2][d] + part[3][d];
    float r = uu + hv;
    // layernorm (all waves redundantly, identical values)
    float sum = r;
#pragma unroll
    for (int o = 32; o; o >>= 1) sum += __shfl_xor(sum, o);
    float mu = sum * (1.f / HH);
    float dr = r - mu;
    float v2 = dr * dr;
#pragma unroll
    for (int o = 32; o; o >>= 1) v2 += __shfl_xor(v2, o);
    float var = v2 * (1.f / HH);
    float hn = lng[d] * dr * (1.f / sqrtf(var + LN_EPS)) + lnb[d];
    if (w == 0) { h_out[(size_t)j * HH + d] = hn; hs[d] = hn; }
    __syncthreads();

    if (do_prep) {
        float pp = (w == 0) ? ab1n[d] : 0.f, qq = 0.f, rr = (w == 0) ? vb1n[d] : 0.f;
        for (int k = w * 16; k < w * 16 + 16; ++k) {
            float hk = hs[k];
            pp += hk * aw1n[k * HH + d];
            qq += hk * aw1n[(HH + k) * HH + d];
            rr += hk * vw1n[k * HH + d];
        }
        part[w][d] = pp; partQ[w][d] = qq; partR[w][d] = rr;
        __syncthreads();
        float qfull = partQ[0][d] + partQ[1][d] + partQ[2][d] + partQ[3][d];
        if (w == 0) {
            Pd[(size_t)j * HH + d] = part[0][d] + part[1][d] + part[2][d] + part[3][d];
            Qs[(size_t)j * HH + d] = qfull;
            Rv[(size_t)j * HH + d] = partR[0][d] + partR[1][d] + partR[2][d] + partR[3][d];
            float sq = qfull * wa2n[d];
#pragma unroll
            for (int o = 32; o; o >>= 1) sq += __shfl_xor(sq, o);
            if (d == 0) Sq[j] = sq;
        }
    }
}

__global__ void k_decoder(const float* __restrict__ h,
                          const float* __restrict__ dw1, const float* __restrict__ db1,
                          const float* __restrict__ dw2, const float* __restrict__ db2,
                          float* __restrict__ out) {
    int j = blockIdx.x, d = threadIdx.x;   // 64 threads
    __shared__ float hs[HH];
    hs[d] = h[(size_t)j * HH + d];
    __syncthreads();
    float t = db1[d];
    for (int k = 0; k < HH; ++k) t += hs[k] * dw1[k * HH + d];
    t = fmaxf(t, 0.f);
    float sum = t * dw2[d];
#pragma unroll
    for (int o = 32; o; o >>= 1) sum += __shfl_xor(sum, o);
    if (d == 0) out[j] = sum + db2[0];
}

extern "C" void kernel_launch(void* const* d_in, const int* in_sizes, int n_in,
                              void* d_out, int out_size, void* d_ws, size_t ws_size,
                              hipStream_t stream) {
    const float* x      = (const float*)d_in[0];
    const float* ea     = (const float*)d_in[1];
    const float* enc_w1 = (const float*)d_in[2];
    const float* enc_b1 = (const float*)d_in[3];
    const float* enc_w2 = (const float*)d_in[4];
    const float* enc_b2 = (const float*)d_in[5];
    const float* att_w1 = (const float*)d_in[6];
    const float* att_b1 = (const float*)d_in[7];
    const float* att_w2 = (const float*)d_in[8];
    // d_in[9] = att_b2: per-layer constant, cancels in softmax — unused
    const float* val_w1 = (const float*)d_in[10];
    const float* val_b1 = (const float*)d_in[11];
    const float* val_w2 = (const float*)d_in[12];
    const float* val_b2 = (const float*)d_in[13];
    const float* upd_w1 = (const float*)d_in[14];
    const float* upd_b1 = (const float*)d_in[15];
    const float* upd_w2 = (const float*)d_in[16];
    const float* upd_b2 = (const float*)d_in[17];
    const float* ln_g   = (const float*)d_in[18];
    const float* ln_b   = (const float*)d_in[19];
    const float* dec_w1 = (const float*)d_in[20];
    const float* dec_b1 = (const float*)d_in[21];
    const float* dec_w2 = (const float*)d_in[22];
    const float* dec_b2 = (const float*)d_in[23];
    // d_in[24] = edge_index: dense regular grid (src=e/N, dst=e%N) — used structurally

    const size_t NH = (size_t)NN * HH;
    const size_t need_full = ((size_t)NN * NN * 6 + 6 * NH + NN) * sizeof(float);
    float* ws = (float*)d_ws;
    const bool trans = (ws_size >= need_full);

    float* EAT  = ws;
    float* base = trans ? ws + (size_t)NN * NN * 6 : ws;
    float* h    = base;
    float* Pd   = h + NH;
    float* Qs   = Pd + NH;
    float* Rv   = Qs + NH;
    float* acc  = Rv + NH;
    float* h2   = acc + NH;
    float* Sq   = h2 + NH;

    if (trans) k_transpose<<<(NN * NN) / 256, 256, 0, stream>>>(ea, EAT);
    k_encoder<<<NN, HH, 0, stream>>>(x, enc_w1, enc_b1, enc_w2, enc_b2,
                                     att_w1, att_b1, att_w2, val_w1, val_b1,
                                     h, Pd, Qs, Rv, Sq);

    const float* easrc = trans ? (const float*)EAT : ea;
    const float* hin = h;
    float* hout = h2;
    for (int l = 0; l < NLAYERS; ++l) {
        const float* aw1 = att_w1 + (size_t)l * 134 * HH;
        const float* vw1 = val_w1 + (size_t)l * 70 * HH;
        if (trans)
            k_edge<true><<<NN, 256, 0, stream>>>(easrc, Pd, Qs, Rv, Sq,
                                                 aw1 + 128 * HH, att_w2 + l * HH,
                                                 vw1 + 64 * HH, acc);
        else
            k_edge<false><<<NN, 256, 0, stream>>>(easrc, Pd, Qs, Rv, Sq,
                                                  aw1 + 128 * HH, att_w2 + l * HH,
                                                  vw1 + 64 * HH, acc);
        int np = (l + 1 < NLAYERS) ? (l + 1) : l;   // clamped (unused when do_prep=0)
        k_node<<<NN, 256, 0, stream>>>(hin, acc,
                                       val_w2 + (size_t)l * HH * HH, val_b2 + l * HH,
                                       upd_w1 + (size_t)l * 2 * HH * HH, upd_b1 + l * HH,
                                       upd_w2 + (size_t)l * HH * HH, upd_b2 + l * HH,
                                       ln_g + l * HH, ln_b + l * HH,
                                       hout,
                                       att_w1 + (size_t)np * 134 * HH, att_b1 + np * HH,
                                       att_w2 + np * HH,
                                       val_w1 + (size_t)np * 70 * HH, val_b1 + np * HH,
                                       Pd, Qs, Rv, Sq, (l + 1 < NLAYERS) ? 1 : 0);
        float* tmp = (float*)hin; hin = hout; hout = tmp;
    }
    k_decoder<<<NN, HH, 0, stream>>>(hin, dec_w1, dec_b1, dec_w2, dec_b2, (float*)d_out);
}